// Round 17
// baseline (247.546 us; speedup 1.0000x reference)
//
#include <hip/hip_runtime.h>

// ResLSTM: B=4096, T=512, H=32.
// R24 = R21 (2 waves, 16 batches, raw-barrier exchange) + REGISTER-RESIDENT
//   OWN-HALF B + READ-EARLY OVERLAP.
//   Insight: lane (c,q) of wave w computes h of units 16w+4q+m for batch c
//   == its own B-fragment K-half. So only the PARTNER half (8B) crosses
//   LDS. Two K=16 MFMAs per tile (order proven bit-safe in R18):
//   acc = MF16(Aown,Bown,acc) [regs] then MF16(Apart,Bpart,acc).
//   Step order: issue partner b64 read FIRST (right after prev barrier);
//   init-fma + 4 own-half MFMAs run under the read latency; then partner
//   MFMAs, GSTATE, cvt->Bown (regs), write own 8B, lgkmcnt(0)+barrier.
// R23 POST-MORTEM: 4-wave barrier idle ~580 vs 2-wave 240 -> barrier cost
//   scales with wave count; chain (not issue) binds. Stay at 2 waves,
//   shorten chain (-read latency hidden, -half MFMA stage post-read).
// History: R7 341. R11 297. R12 dot2 248. R14 230. R16 219 (VALU floor).
//   R18 K=16 305. R19 K=32 279. R20 2-wave 197. R21 raw barrier 183.7.
//   R22 2-groups/wave 338 (reverted). R23 4-wave 192.9 (reverted).
// Predict: 861 -> ~730-780 cy/step -> 155-170 us; VALUBusy(CU) 34-37%;
//   MfmaUtil 3.6-4.5; absmax ~0.0009765625. Failure >=180: chain model
//   wrong -> R21-class structure near-floor.

static constexpr int T_LEN = 512;
static constexpr int H = 32;

typedef _Float16 h2   __attribute__((ext_vector_type(2)));
typedef __fp16   fp2  __attribute__((ext_vector_type(2)));   // cvt_pkrtz type
typedef _Float16 v4h  __attribute__((ext_vector_type(4)));
typedef float    v4f  __attribute__((ext_vector_type(4)));

// D = A(4 f16) x B(4 f16) + C(4 f32), 16x16x16 f16 MFMA.
__device__ __forceinline__ v4f MF16(v4h a, v4h b, v4f c) {
#if __has_builtin(__builtin_amdgcn_mfma_f32_16x16x16f16)
    return __builtin_amdgcn_mfma_f32_16x16x16f16(a, b, c, 0, 0, 0);
#else
    v4f d = c;
    asm("v_mfma_f32_16x16x16_f16 %0, %1, %2, %0" : "+v"(d) : "v"(a), "v"(b));
    return d;
#endif
}

__device__ __forceinline__ v4h comb4(fp2 a, fp2 b) {
    union { h2 p[2]; v4h v; } u;
    u.p[0] = __builtin_bit_cast(h2, a);
    u.p[1] = __builtin_bit_cast(h2, b);
    return u.v;
}

__device__ __forceinline__ v4h mkB4(uint2 w) {
    union { uint2 u; v4h v; } u;
    u.u = w; return u.v;
}

__global__ void
__attribute__((amdgpu_flat_work_group_size(128, 128), amdgpu_waves_per_eu(1, 1)))
reslstm_kernel(const float* __restrict__ x,
               const float* __restrict__ W_ih,
               const float* __restrict__ W_hh,
               const float* __restrict__ b_ih,
               const float* __restrict__ b_hh,
               const float* __restrict__ W_fc,
               const float* __restrict__ b_fc,
               float* __restrict__ out, int B)
{
    // x chunk: [batch-col][t], pad 36.
    __shared__ float xl[16][36];
    // h exchange, parity-buffered: [buf][q][c][wave] 8B slots.
    __shared__ uint2 hx[2][4][16][2];
    __shared__ float osum[2][16];

    const int tid  = threadIdx.x;
    const int lane = tid & 63;
    const int wv   = tid >> 6;           // wave 0: units 0-15, wave 1: 16-31
    const int c    = lane & 15;          // batch col (0..15)
    const int q    = lane >> 4;          // row quad  (0..3)

    const int wbase = blockIdx.x << 4;   // 16 batches per block
    if (wbase >= B) return;              // block-uniform guard
    const int bb = wbase + c;

    constexpr float NL2E  = -1.4426950408889634f;   // -log2(e)
    constexpr float N2L2E = 2.0f * NL2E;

    // A fragments, split in K-halves: tile t = 2k + wv (gate k, unit-half wv).
    //   Ak0[k][m] = Whh_sc[16t + c][4q + m]       (K-half 0: units 0-15)
    //   Ak1[k][m] = Whh_sc[16t + c][16 + 4q + m]  (K-half 1: units 16-31)
    // Prescale: g gate (k==2) by 2*-log2(e), else -log2(e).
    v4h Aown[4], Apart[4];
    v4f wih[4], bsb[4];
    #pragma unroll
    for (int k = 0; k < 4; ++k) {
        const int   t  = 2 * k + wv;
        const float sc = (k == 2) ? N2L2E : NL2E;
        const float4 w1 = *reinterpret_cast<const float4*>(
            W_hh + (16 * t + c) * H + 4 * q);
        const float4 w2 = *reinterpret_cast<const float4*>(
            W_hh + (16 * t + c) * H + 16 + 4 * q);
        v4h a0, a1;
        a0[0] = (_Float16)(w1.x * sc); a0[1] = (_Float16)(w1.y * sc);
        a0[2] = (_Float16)(w1.z * sc); a0[3] = (_Float16)(w1.w * sc);
        a1[0] = (_Float16)(w2.x * sc); a1[1] = (_Float16)(w2.y * sc);
        a1[2] = (_Float16)(w2.z * sc); a1[3] = (_Float16)(w2.w * sc);
        // wave0 owns K-half 0 (its units), wave1 owns K-half 1.
        Aown[k]  = (wv == 0) ? a0 : a1;
        Apart[k] = (wv == 0) ? a1 : a0;
        const int r0 = 16 * t + 4 * q;
        const float4 wi = *reinterpret_cast<const float4*>(W_ih + r0);
        const float4 bi = *reinterpret_cast<const float4*>(b_ih + r0);
        const float4 bh = *reinterpret_cast<const float4*>(b_hh + r0);
        wih[k][0] = wi.x * sc; wih[k][1] = wi.y * sc;
        wih[k][2] = wi.z * sc; wih[k][3] = wi.w * sc;
        bsb[k][0] = (bi.x + bh.x) * sc; bsb[k][1] = (bi.y + bh.y) * sc;
        bsb[k][2] = (bi.z + bh.z) * sc; bsb[k][3] = (bi.w + bh.w) * sc;
    }

    // State: this wave's 4 units (16wv + 4q + m).
    float cs0 = 0.f, cs1 = 0.f, cs2 = 0.f, cs3 = 0.f;
    float hv0 = 0.f, hv1 = 0.f, hv2 = 0.f, hv3 = 0.f;
    v4h Bown = comb4(__builtin_amdgcn_cvt_pkrtz(0.f, 0.f),
                     __builtin_amdgcn_cvt_pkrtz(0.f, 0.f));   // own h(0)=0

    // Pre-zero buf[1] (read by the first STEP) and stage sync below.
    hx[1][q][c][wv] = uint2{0u, 0u};

// Light pins once per chunk (R6 lesson: asm outputs can't be rematerialized
// from memory; R13: placement neutral).
#define PINALL()                                                              \
    asm volatile("" : "+v"(Aown[0]), "+v"(Aown[1]), "+v"(Aown[2]),            \
                      "+v"(Aown[3]), "+v"(Apart[0]), "+v"(Apart[1]),          \
                      "+v"(Apart[2]), "+v"(Apart[3]));                        \
    asm volatile("" : "+v"(wih[0]), "+v"(wih[1]), "+v"(wih[2]), "+v"(wih[3]), \
                      "+v"(bsb[0]), "+v"(bsb[1]), "+v"(bsb[2]), "+v"(bsb[3]))

// R14 exp2 gate math (accums prescaled by -log2(e)):
//   c' = [c*Di*Dg + (1-Eg)*Df] * rcp(Df*Di*Dg);  h = (1-Ec) * rcp(Do*Dc).
#define GSTATE(AI, AF, AG, AO, CC, HH) do {                                   \
    const float Ei = __builtin_amdgcn_exp2f(AI);                              \
    const float Ef = __builtin_amdgcn_exp2f(AF);                              \
    const float Eg = __builtin_amdgcn_exp2f(AG);                              \
    const float Eo = __builtin_amdgcn_exp2f(AO);                              \
    const float Di = 1.0f + Ei, Df = 1.0f + Ef;                               \
    const float Dg = 1.0f + Eg, Do_ = 1.0f + Eo;                              \
    const float P  = Di * Dg;                                                 \
    const float t_ = (1.0f - Eg) * Df;                                        \
    const float u_ = __builtin_fmaf(CC, P, t_);                               \
    const float Rc = __builtin_amdgcn_rcpf(Df * P);                           \
    CC = u_ * Rc;                                                             \
    const float Ec = __builtin_amdgcn_exp2f(CC * N2L2E);                      \
    const float Dc = 1.0f + Ec;                                               \
    const float Rh = __builtin_amdgcn_rcpf(Do_ * Dc);                         \
    HH = (1.0f - Ec) * Rh;                                                    \
} while (0)

// One time step. PW = write buf, PRd = PW^1 = read buf (h(t-1) partner).
// Read issued FIRST; init-fma + own-half MFMAs hide its latency; partner
// MFMAs after; GSTATE; cvt->Bown (regs); write own 8B; lgkmcnt+barrier.
#define STEP(XT, PW, PRd) do {                                                \
    const v4h Bpart = mkB4(hx[PRd][q][c][wv ^ 1]);  /* early b64 read */      \
    const float xt = (XT);                                                    \
    v4f acc[4];                                                               \
    _Pragma("unroll")                                                         \
    for (int k = 0; k < 4; ++k) acc[k] = bsb[k] + wih[k] * xt;                \
    _Pragma("unroll")                                                         \
    for (int k = 0; k < 4; ++k) acc[k] = MF16(Aown[k], Bown, acc[k]);         \
    _Pragma("unroll")                                                         \
    for (int k = 0; k < 4; ++k) acc[k] = MF16(Apart[k], Bpart, acc[k]);       \
    unsigned int* slot =                                                      \
        reinterpret_cast<unsigned int*>(&hx[PW][q][c][wv]);                   \
    GSTATE(acc[0][0], acc[1][0], acc[2][0], acc[3][0], cs0, hv0);             \
    GSTATE(acc[0][1], acc[1][1], acc[2][1], acc[3][1], cs1, hv1);             \
    const fp2 pk01 = __builtin_amdgcn_cvt_pkrtz(hv0, hv1);                    \
    slot[0] = __builtin_bit_cast(unsigned int, pk01);                         \
    GSTATE(acc[0][2], acc[1][2], acc[2][2], acc[3][2], cs2, hv2);             \
    GSTATE(acc[0][3], acc[1][3], acc[2][3], acc[3][3], cs3, hv3);             \
    const fp2 pk23 = __builtin_amdgcn_cvt_pkrtz(hv2, hv3);                    \
    slot[1] = __builtin_bit_cast(unsigned int, pk23);                         \
    Bown = comb4(pk01, pk23);                                                 \
    asm volatile("s_waitcnt lgkmcnt(0)\n\ts_barrier" ::: "memory");           \
} while (0)

    // x staging: thread tid owns row r=tid>>3, cols colb..colb+3 of chunk.
    const int r    = tid >> 3;
    const int colb = (tid & 7) << 2;
    const float* xsrc = x + (size_t)(wbase + r) * T_LEN + colb;
    float4 xA = *reinterpret_cast<const float4*>(xsrc);

    for (int tc = 0; tc < T_LEN / 32; ++tc) {
        PINALL();
        *reinterpret_cast<float4*>(&xl[r][colb]) = xA;
        __syncthreads();                  // stage (and buf[1] zero) visible
        if (tc + 1 < T_LEN / 32)
            xA = *reinterpret_cast<const float4*>(xsrc + (tc + 1) * 32);
        const float4* xq4c = reinterpret_cast<const float4*>(&xl[c][0]);
        #pragma unroll 2
        for (int t4 = 0; t4 < 8; ++t4) {
            const float4 xv = xq4c[t4];   // 4 steps of x in regs
            STEP(xv.x, 0, 1);
            STEP(xv.y, 1, 0);
            STEP(xv.z, 0, 1);
            STEP(xv.w, 1, 0);
        }
    }
#undef STEP
#undef GSTATE
#undef PINALL

    // out[bb] = sum_u h[u]*W_fc[u] + b_fc. This wave: units 16wv+4q+m.
    const int u0 = 16 * wv + 4 * q;
    float val = hv0 * W_fc[u0]     + hv1 * W_fc[u0 + 1]
              + hv2 * W_fc[u0 + 2] + hv3 * W_fc[u0 + 3];
    val += __shfl_xor(val, 16);
    val += __shfl_xor(val, 32);
    if (q == 0) osum[wv][c] = val;
    __syncthreads();
    if (wv == 0 && q == 0 && bb < B)
        out[bb] = osum[0][c] + osum[1][c] + b_fc[0];
}

extern "C" void kernel_launch(void* const* d_in, const int* in_sizes, int n_in,
                              void* d_out, int out_size, void* d_ws, size_t ws_size,
                              hipStream_t stream) {
    const float* x    = (const float*)d_in[0];
    const float* W_ih = (const float*)d_in[1];
    const float* W_hh = (const float*)d_in[2];
    const float* b_ih = (const float*)d_in[3];
    const float* b_hh = (const float*)d_in[4];
    const float* W_fc = (const float*)d_in[5];
    const float* b_fc = (const float*)d_in[6];
    float* out = (float*)d_out;
    const int B = in_sizes[0] / T_LEN;        // 4096
    dim3 block(128);                          // 2 waves = 16 batch elements
    dim3 grid((B + 15) / 16);                 // 256 blocks -> 2 SIMDs/CU
    reslstm_kernel<<<grid, block, 0, stream>>>(x, W_ih, W_hh, b_ih, b_hh,
                                               W_fc, b_fc, out, B);
}